// Round 5
// baseline (245.879 us; speedup 1.0000x reference)
//
#include <hip/hip_runtime.h>
#include <stdint.h>

#define NB 256
#define NL 128
#define ND1 512
#define ND2 512

#define BI 64               // i-tile width per block
#define NKT 16              // k-tiles of 32 over ND2=512

typedef float float4_t __attribute__((ext_vector_type(4)));
typedef __bf16 bf16x8_t __attribute__((ext_vector_type(8)));
typedef unsigned short ushort8_t __attribute__((ext_vector_type(8)));

// fp32 -> bf16 round-to-nearest-even
__device__ __forceinline__ unsigned short f2bf(float f) {
    unsigned int u = __float_as_uint(f);
    u += 0x7FFFu + ((u >> 16) & 1u);
    return (unsigned short)(u >> 16);
}

// out[b,l] = sum_ij t1[b,l,i] W[e,i,j] t2[b,l,j]
// GEMM: Z = T2 * W^T  (A = t2 rows, k=j contiguous; B = W rows, k=j contiguous)
// W slab (64 i x 512 j, bf16, XOR-swizzled) lives in LDS for the whole kernel:
// ONE barrier total, k-loop is barrier-free -> global A loads pipeline freely.
__global__ __launch_bounds__(512, 4) void pdot_kernel(
    const float* __restrict__ t1, const float* __restrict__ t2,
    const int* __restrict__ pidx, const float* __restrict__ wgt,
    float* __restrict__ out)
{
    __shared__ unsigned short sW[BI * ND2];   // 65536 B exactly; chunk c (8 bf16) stored at c^(row&7)

    const int g  = blockIdx.x;
    const int b  = g & (NB - 1);   // all 8 i-tiles of batch b share g%8 -> same XCD -> t2 L2 reuse
    const int it = g >> 8;
    const int i0 = it * BI;

    const int t  = threadIdx.x;    // 0..511
    const int wv = t >> 6;         // wave 0..7 -> l-rows wv*16..wv*16+15
    const int ln = t & 63;
    const int nh = ln & 15;
    const int qd = ln >> 4;

    const int e = pidx[b];
    const float* wp = wgt + (size_t)e * (ND1 * ND2) + (size_t)i0 * ND2;

    // ---- stage W slab -> LDS bf16, once. thread t: row r=t>>3, 8 chunks of 8 floats.
    {
        const int r  = t >> 3;         // 0..63
        const int c8 = t & 7;
        const int sw = r & 7;
        const float* src = wp + (size_t)r * ND2;
        unsigned short* dst = &sW[r * ND2];
        #pragma unroll
        for (int q = 0; q < 8; ++q) {
            const int c = c8 + 8 * q;              // chunk index 0..63
            float4_t lo = *(const float4_t*)(src + c * 8);
            float4_t hi = *(const float4_t*)(src + c * 8 + 4);
            ushort8_t u;
            u[0] = f2bf(lo.x); u[1] = f2bf(lo.y); u[2] = f2bf(lo.z); u[3] = f2bf(lo.w);
            u[4] = f2bf(hi.x); u[5] = f2bf(hi.y); u[6] = f2bf(hi.z); u[7] = f2bf(hi.w);
            *(ushort8_t*)(dst + ((c ^ sw) * 8)) = u;
        }
    }
    __syncthreads();   // the ONLY barrier

    // ---- barrier-free k-loop. A-fragment straight from global:
    // A[m=nh][k=qd*8+j] -> t2[b, wv*16+nh, kt*32+qd*8 .. +7]
    const float* aRow = t2 + (size_t)b * (NL * ND2) + (size_t)(wv * 16 + nh) * ND2;
    const int swz = nh & 7;
    const unsigned short* wBase = &sW[nh * ND2];   // + ns*16*ND2 + chunk-offset

    float4_t acc[4];
    #pragma unroll
    for (int ns = 0; ns < 4; ++ns) { float4_t z = {0.f,0.f,0.f,0.f}; acc[ns] = z; }

    float4_t a_lo = *(const float4_t*)(aRow + qd * 8);
    float4_t a_hi = *(const float4_t*)(aRow + qd * 8 + 4);

    #pragma unroll
    for (int kt = 0; kt < NKT; ++kt) {
        float4_t n_lo, n_hi;
        if (kt < NKT - 1) {
            n_lo = *(const float4_t*)(aRow + (kt + 1) * 32 + qd * 8);
            n_hi = *(const float4_t*)(aRow + (kt + 1) * 32 + qd * 8 + 4);
        }
        ushort8_t ua;
        ua[0] = f2bf(a_lo.x); ua[1] = f2bf(a_lo.y); ua[2] = f2bf(a_lo.z); ua[3] = f2bf(a_lo.w);
        ua[4] = f2bf(a_hi.x); ua[5] = f2bf(a_hi.y); ua[6] = f2bf(a_hi.z); ua[7] = f2bf(a_hi.w);
        bf16x8_t af = __builtin_bit_cast(bf16x8_t, ua);

        const int co = ((kt * 4 + qd) ^ swz) * 8;   // swizzled chunk offset (elems), same for all ns
        #pragma unroll
        for (int ns = 0; ns < 4; ++ns) {
            bf16x8_t bfr = __builtin_bit_cast(bf16x8_t,
                *(const ushort8_t*)(wBase + ns * 16 * ND2 + co));
            acc[ns] = __builtin_amdgcn_mfma_f32_16x16x32_bf16(af, bfr, acc[ns], 0, 0, 0);
        }
        a_lo = n_lo; a_hi = n_hi;
    }

    // ---- epilogue: out[b,l] += sum_i Z[l,i]*t1[b,l,i] over this i-tile
    // C/D: col(i) = ns*16+nh, row(l) = wv*16 + qd*4 + r
    const float* t1p = t1 + (size_t)b * (NL * ND1) + i0;
    #pragma unroll
    for (int r = 0; r < 4; ++r) {
        const int row = wv * 16 + qd * 4 + r;
        float ps = 0.f;
        #pragma unroll
        for (int ns = 0; ns < 4; ++ns)
            ps += acc[ns][r] * t1p[(size_t)row * ND1 + ns * 16 + nh];
        ps += __shfl_xor(ps, 1);
        ps += __shfl_xor(ps, 2);
        ps += __shfl_xor(ps, 4);
        ps += __shfl_xor(ps, 8);
        if (nh == 0) atomicAdd(&out[b * NL + row], ps);
    }
}

extern "C" void kernel_launch(void* const* d_in, const int* in_sizes, int n_in,
                              void* d_out, int out_size, void* d_ws, size_t ws_size,
                              hipStream_t stream)
{
    const float* t1  = (const float*)d_in[0];
    const float* t2  = (const float*)d_in[1];
    const int* pidx  = (const int*)d_in[2];
    const float* wgt = (const float*)d_in[3];
    float* out = (float*)d_out;

    hipMemsetAsync(out, 0, (size_t)out_size * sizeof(float), stream);
    pdot_kernel<<<dim3(NB * (ND1 / BI)), dim3(512), 0, stream>>>(t1, t2, pidx, wgt, out);
}